// Round 3
// baseline (206.993 us; speedup 1.0000x reference)
//
#include <hip/hip_runtime.h>
#include <math.h>

#define NB   8
#define NK   64
#define NL   1024
#define NCP  32
#define NAP  8
#define NG2  9
#define NCSA 16
#define NASA 16
#define NG3  3
#define NOC  256      // = NCP*NAP = NCSA*NASA
#define EPSQ 1e-8f
#define LT   8        // l-positions per block in kernel 1

// ---------------- Kernel 1: conv1 (k=9, SAME) + bias + squash(ap=8) ----------
// grid = NB * (NL/LT) = 1024 blocks, 256 threads (thread = output channel oc)
// launch_bounds(256,2): cap ~128 VGPR -> no spill (natural ~70-90)
__global__ __launch_bounds__(256, 2) void k1_conv1_squash(
    const float* __restrict__ x, const float* __restrict__ w1,
    const float* __restrict__ b1, float* __restrict__ ysq)
{
    __shared__ alignas(16) float xs[NK][LT + NG2 - 1];   // [64][16] = 4 KB
    const int tid = threadIdx.x;
    const int bid = blockIdx.x;
    const int b   = bid >> 7;            // 128 = NL/LT
    const int l0  = (bid & 127) * LT;

    const float* xb = x + (size_t)b * NK * NL;
    for (int i = tid; i < NK * (LT + 8); i += 256) {
        int row = i >> 4, col = i & 15;
        int l = l0 + col - 4;
        xs[row][col] = (l >= 0 && l < NL) ? xb[row * NL + l] : 0.0f;
    }

    float acc[LT];
    {
        float bb = b1[tid];
#pragma unroll
        for (int i = 0; i < LT; ++i) acc[i] = bb;
    }
    __syncthreads();

    const float* wrow = w1 + (size_t)tid * (NK * NG2);   // this oc's weights
    // process k in groups of 4: 36 floats = 9 float4 (16B-aligned at k%4==0)
    for (int k4 = 0; k4 < NK; k4 += 4) {
        float wk[36];
        const float4* wp4 = (const float4*)(wrow + k4 * NG2);
#pragma unroll
        for (int q = 0; q < 9; ++q) {
            float4 v = wp4[q];
            wk[q*4+0]=v.x; wk[q*4+1]=v.y; wk[q*4+2]=v.z; wk[q*4+3]=v.w;
        }
#pragma unroll
        for (int kk = 0; kk < 4; ++kk) {
            float xr[LT + NG2 - 1];
            const float4* xrow4 = (const float4*)(&xs[k4 + kk][0]);
#pragma unroll
            for (int q = 0; q < 4; ++q) {
                float4 v = xrow4[q];
                xr[q*4+0] = v.x; xr[q*4+1] = v.y; xr[q*4+2] = v.z; xr[q*4+3] = v.w;
            }
#pragma unroll
            for (int l = 0; l < LT; ++l)
#pragma unroll
                for (int g = 0; g < NG2; ++g)
                    acc[l] = fmaf(xr[l + g], wk[kk * NG2 + g], acc[l]);
        }
    }

    // squash over ap = groups of 8 consecutive lanes (oc = cp*8+ap)
    float* yb = ysq + ((size_t)b * NL + l0) * NOC + tid;
#pragma unroll
    for (int l = 0; l < LT; ++l) {
        float sq = acc[l] * acc[l];
        sq += __shfl_xor(sq, 1);
        sq += __shfl_xor(sq, 2);
        sq += __shfl_xor(sq, 4);
        float val = sq / (1.0f + sq) * acc[l] / sqrtf(sq + EPSQ);
        yb[(size_t)l * NOC] = val;     // coalesced
    }
}

// ---------------- Kernel 2: conv2 (3x8 stride 8) + dynamic routing (3 iters) --
// grid = NB*NL = 8192 blocks (one (b,l) site), 256 threads
// V-compute: 2 passes of (2 cp x 8 oc) per thread: yr[2][24]=48 regs, no spill.
__global__ __launch_bounds__(256, 3) void k2_conv2_routing(
    const float* __restrict__ ysq, const float* __restrict__ w2,
    const float* __restrict__ b2, float* __restrict__ out)
{
    __shared__ float VT[NOC][NCP + 1];      // V transposed [oc][cp], pad 33: 33.8 KB
    __shared__ float br[NCP][NCSA + 1];     // routing logits   2.1 KB
    __shared__ float cc[NCP][NCSA + 1];     // softmax coeffs   2.1 KB
    __shared__ float vv[NCSA][NASA + 1];    // squashed v       1.1 KB  -> 39.2 KB

    const int tid = threadIdx.x;
    const int bid = blockIdx.x;
    const int b = bid >> 10;
    const int l = bid & (NL - 1);

    const int ocg = tid & 31;
    const int cpg = tid >> 5;

    const float* base = ysq + ((size_t)b * NL + l) * NOC;
    const bool vlo = (l >= 1), vhi = (l < NL - 1);

#pragma unroll
    for (int pass = 0; pass < 2; ++pass) {
        const int cp0 = cpg + 16 * pass;
        const int cp1 = cp0 + 8;
        float yr[2][24];
#pragma unroll
        for (int ci = 0; ci < 2; ++ci) {
            const int cp = (ci == 0) ? cp0 : cp1;
            const float* p1 = base + cp * 8;     // row l, this cp's 8 ap values
#pragma unroll
            for (int g = 0; g < 3; ++g) {
                const bool ok = (g == 0) ? vlo : (g == 2) ? vhi : true;
                float4 a = {0.f, 0.f, 0.f, 0.f}, q2 = {0.f, 0.f, 0.f, 0.f};
                if (ok) {   // wave-uniform branch
                    const float4* p = (const float4*)(p1 + (g - 1) * NOC);
                    a = p[0]; q2 = p[1];
                }
                yr[ci][g*8+0]=a.x;  yr[ci][g*8+1]=a.y;  yr[ci][g*8+2]=a.z;  yr[ci][g*8+3]=a.w;
                yr[ci][g*8+4]=q2.x; yr[ci][g*8+5]=q2.y; yr[ci][g*8+6]=q2.z; yr[ci][g*8+7]=q2.w;
            }
        }
        for (int j = 0; j < 8; ++j) {
            const int oc = ocg + 32 * j;
            const float4* wp4 = (const float4*)(w2 + oc * 24);   // 96B-aligned
            const float bias = b2[oc];
            float a0 = bias, a1 = bias;
#pragma unroll
            for (int q = 0; q < 6; ++q) {
                float4 w = wp4[q];
                a0 = fmaf(yr[0][q*4+0], w.x, a0); a0 = fmaf(yr[0][q*4+1], w.y, a0);
                a0 = fmaf(yr[0][q*4+2], w.z, a0); a0 = fmaf(yr[0][q*4+3], w.w, a0);
                a1 = fmaf(yr[1][q*4+0], w.x, a1); a1 = fmaf(yr[1][q*4+1], w.y, a1);
                a1 = fmaf(yr[1][q*4+2], w.z, a1); a1 = fmaf(yr[1][q*4+3], w.w, a1);
            }
            VT[oc][cp0] = a0;
            VT[oc][cp1] = a1;
        }
    }
    __syncthreads();

    // ---- routing ----
    const int cp_s = tid >> 3, cs = tid & 7;     // softmax/a-step mapping
    const int csa  = tid >> 4, asa = tid & 15;   // s-step mapping (tid == oc)

    // own VT row is iteration-invariant: hoist to registers
    float Vreg[NCP];
#pragma unroll
    for (int cp = 0; cp < NCP; ++cp) Vreg[cp] = VT[tid][cp];

    // ---- r = 0: b == 0 -> softmax is uniform 1/16
    {
        float sv = 0.0f;
#pragma unroll
        for (int cp = 0; cp < NCP; ++cp) sv += Vreg[cp];
        sv *= 0.0625f;
        float sq = sv * sv;
        sq += __shfl_xor(sq, 1);
        sq += __shfl_xor(sq, 2);
        sq += __shfl_xor(sq, 4);
        sq += __shfl_xor(sq, 8);
        float vval = sq / (1.0f + sq) * sv / sqrtf(sq + EPSQ);
        vv[csa][asa] = vval;
        __syncthreads();
        float a0 = 0.0f, a1 = 0.0f;
#pragma unroll
        for (int q = 0; q < NASA; ++q) {
            a0 = fmaf(VT[cs * 16 + q][cp_s],       vv[cs][q],     a0);
            a1 = fmaf(VT[(cs + 8) * 16 + q][cp_s], vv[cs + 8][q], a1);
        }
        br[cp_s][cs]     = a0;   // b was 0: assign
        br[cp_s][cs + 8] = a1;
        __syncthreads();
    }

    // ---- r = 1, 2
    for (int r = 1; r < 3; ++r) {
        float t0 = br[cp_s][cs], t1 = br[cp_s][cs + 8];
        float m = fmaxf(t0, t1);
        m = fmaxf(m, __shfl_xor(m, 1));
        m = fmaxf(m, __shfl_xor(m, 2));
        m = fmaxf(m, __shfl_xor(m, 4));
        float e0 = __expf(t0 - m), e1 = __expf(t1 - m);
        float ssum = e0 + e1;
        ssum += __shfl_xor(ssum, 1);
        ssum += __shfl_xor(ssum, 2);
        ssum += __shfl_xor(ssum, 4);
        float inv = 1.0f / ssum;
        cc[cp_s][cs]     = e0 * inv;
        cc[cp_s][cs + 8] = e1 * inv;
        __syncthreads();

        float sv = 0.0f;
#pragma unroll
        for (int cp = 0; cp < NCP; ++cp)
            sv = fmaf(cc[cp][csa], Vreg[cp], sv);
        float sq = sv * sv;
        sq += __shfl_xor(sq, 1);
        sq += __shfl_xor(sq, 2);
        sq += __shfl_xor(sq, 4);
        sq += __shfl_xor(sq, 8);
        float vval = sq / (1.0f + sq) * sv / sqrtf(sq + EPSQ);

        if (r == 2) {
            out[((size_t)b * NL + l) * NOC + tid] = vval;   // coalesced
        } else {
            vv[csa][asa] = vval;
            __syncthreads();
            float a0 = 0.0f, a1 = 0.0f;
#pragma unroll
            for (int q = 0; q < NASA; ++q) {
                a0 = fmaf(VT[cs * 16 + q][cp_s],       vv[cs][q],     a0);
                a1 = fmaf(VT[(cs + 8) * 16 + q][cp_s], vv[cs + 8][q], a1);
            }
            br[cp_s][cs]     += a0;
            br[cp_s][cs + 8] += a1;
            __syncthreads();
        }
    }
}

extern "C" void kernel_launch(void* const* d_in, const int* in_sizes, int n_in,
                              void* d_out, int out_size, void* d_ws, size_t ws_size,
                              hipStream_t stream)
{
    const float* x  = (const float*)d_in[0];
    const float* w1 = (const float*)d_in[1];
    const float* b1 = (const float*)d_in[2];
    const float* w2 = (const float*)d_in[3];
    const float* b2 = (const float*)d_in[4];
    float* outp = (float*)d_out;
    float* ysq  = (float*)d_ws;            // 8*1024*256*4 = 8 MB scratch

    k1_conv1_squash<<<NB * (NL / LT), 256, 0, stream>>>(x, w1, b1, ysq);
    k2_conv2_routing<<<NB * NL, 256, 0, stream>>>(ysq, w2, b2, outp);
}

// Round 4
// 155.115 us; speedup vs baseline: 1.3345x; 1.3345x over previous
//
#include <hip/hip_runtime.h>
#include <math.h>

#define NB   8
#define NK   64
#define NL   1024
#define NCP  32
#define NAP  8
#define NG2  9
#define NCSA 16
#define NASA 16
#define NG3  3
#define NOC  256      // = NCP*NAP = NCSA*NASA
#define EPSQ 1e-8f

typedef __bf16 bfv8 __attribute__((ext_vector_type(8)));
typedef float  f32x4 __attribute__((ext_vector_type(4)));

// ---------------- Kernel 1: conv1 (k=9, SAME) + bias + squash(ap=8) ----------
// Retiled: block = 32 oc x 64 l. grid = 8 ocg * 16 ltile * 8 b = 1024 blocks.
// Weight footprint per block: 32 oc x 2.3KB = 74KB (L1/L2-resident, 8x less
// traffic than previous full-256-oc blocks).
__global__ __launch_bounds__(256, 4) void k1_conv1_squash(
    const float* __restrict__ x, const float* __restrict__ w1,
    const float* __restrict__ b1, float* __restrict__ ysq)
{
    __shared__ alignas(16) float xs[NK][72];   // 64 x 72 floats = 18 KB
    const int tid = threadIdx.x;
    const int bid = blockIdx.x;
    const int og = bid & 7;
    const int lt = (bid >> 3) & 15;
    const int b  = bid >> 7;
    const int l0 = lt * 64;

    const float* xb = x + (size_t)b * NK * NL;
    for (int idx = tid; idx < NK * 72; idx += 256) {
        int row = idx / 72, col = idx - row * 72;
        int l = l0 + col - 4;
        xs[row][col] = (l >= 0 && l < NL) ? xb[row * NL + l] : 0.0f;
    }

    const int ocl = tid & 31, lg = tid >> 5;
    const int oc  = og * 32 + ocl;

    float acc[8];
    {
        float bb = b1[oc];
#pragma unroll
        for (int i = 0; i < 8; ++i) acc[i] = bb;
    }
    __syncthreads();

    const float* wrow = w1 + (size_t)oc * (NK * NG2);
    for (int k4 = 0; k4 < NK; k4 += 4) {
        float wk[36];
        const float4* wp4 = (const float4*)(wrow + k4 * NG2);
#pragma unroll
        for (int q = 0; q < 9; ++q) {
            float4 v = wp4[q];
            wk[q*4+0]=v.x; wk[q*4+1]=v.y; wk[q*4+2]=v.z; wk[q*4+3]=v.w;
        }
#pragma unroll
        for (int kk = 0; kk < 4; ++kk) {
            float xr[16];
            const float4* xrow4 = (const float4*)(&xs[k4 + kk][lg * 8]);
#pragma unroll
            for (int q = 0; q < 4; ++q) {
                float4 v = xrow4[q];
                xr[q*4+0]=v.x; xr[q*4+1]=v.y; xr[q*4+2]=v.z; xr[q*4+3]=v.w;
            }
#pragma unroll
            for (int l = 0; l < 8; ++l)
#pragma unroll
                for (int g = 0; g < NG2; ++g)
                    acc[l] = fmaf(xr[l + g], wk[kk * NG2 + g], acc[l]);
        }
    }

    // squash over ap: lanes (lg&1)*32 + ocl; ap = ocl&7 -> 8 adjacent lanes
#pragma unroll
    for (int l = 0; l < 8; ++l) {
        float sq = acc[l] * acc[l];
        sq += __shfl_xor(sq, 1);
        sq += __shfl_xor(sq, 2);
        sq += __shfl_xor(sq, 4);
        float val = sq / (1.0f + sq) * acc[l] / sqrtf(sq + EPSQ);
        ysq[((size_t)b * NL + l0 + lg * 8 + l) * NOC + oc] = val;
    }
}

// ---------------- Kernel 2: conv2 via split-bf16 MFMA + dynamic routing ------
// grid = NB*NL = 8192 blocks (one (b,l) site), 256 threads = 4 waves.
// GEMM: C[256 oc][32 cp] = W[256][24] * Ypatch[24][32], K padded to 32.
// Split fp32 = bf16_hi + bf16_lo; C = Ahi*Bhi + Ahi*Blo + Alo*Bhi (fp32 acc).
__device__ inline void frag_from8(const float* p, bool ok, bfv8& hi, bfv8& lo)
{
    if (ok) {
        float4 a = ((const float4*)p)[0];
        float4 c = ((const float4*)p)[1];
        float v[8] = {a.x, a.y, a.z, a.w, c.x, c.y, c.z, c.w};
#pragma unroll
        for (int i = 0; i < 8; ++i) {
            __bf16 h = (__bf16)v[i];
            hi[i] = h;
            lo[i] = (__bf16)(v[i] - (float)h);
        }
    } else {
#pragma unroll
        for (int i = 0; i < 8; ++i) { hi[i] = (__bf16)0.0f; lo[i] = (__bf16)0.0f; }
    }
}

__global__ __launch_bounds__(256, 4) void k2_conv2_routing(
    const float* __restrict__ ysq, const float* __restrict__ w2,
    const float* __restrict__ b2, float* __restrict__ out)
{
    __shared__ float VT[NOC][NCP + 1];      // V transposed [oc][cp], pad 33: 33.8 KB
    __shared__ float br[NCP][NCSA + 1];     // routing logits   2.1 KB
    __shared__ float cc[NCP][NCSA + 1];     // softmax coeffs   2.1 KB
    __shared__ float vv[NCSA][NASA + 1];    // squashed v       1.1 KB  -> 39.2 KB

    const int tid = threadIdx.x;
    const int bid = blockIdx.x;
    const int b = bid >> 10;
    const int l = bid & (NL - 1);

    const int lane = tid & 63;
    const int wv   = tid >> 6;          // wave 0..3
    const int q    = lane >> 4;         // k-chunk group 0..3 (chunk 3 = zero pad)
    const int cr   = lane & 15;         // A-row / B-col within tile

    // ---- B fragments (y patch), both col-tiles, straight from global ----
    const float* ybase = ysq + ((size_t)b * NL + l) * NOC;
    const bool rowok = (q == 1) || (q == 0 && l > 0) || (q == 2 && l < NL - 1);
    bfv8 Bhi0, Blo0, Bhi1, Blo1;
    frag_from8(ybase + (q - 1) * NOC + cr * 8,        rowok, Bhi0, Blo0);
    frag_from8(ybase + (q - 1) * NOC + (cr + 16) * 8, rowok, Bhi1, Blo1);

    // ---- 4 oc-tiles per wave: A frags + 6 MFMAs each ----
#pragma unroll
    for (int i = 0; i < 4; ++i) {
        const int t  = wv * 4 + i;
        const int oc = t * 16 + cr;                 // A row
        bfv8 Ahi, Alo;
        frag_from8(w2 + oc * 24 + q * 8, q < 3, Ahi, Alo);

        f32x4 acc0 = {0.f, 0.f, 0.f, 0.f};
        f32x4 acc1 = {0.f, 0.f, 0.f, 0.f};
        acc0 = __builtin_amdgcn_mfma_f32_16x16x32_bf16(Ahi, Bhi0, acc0, 0, 0, 0);
        acc1 = __builtin_amdgcn_mfma_f32_16x16x32_bf16(Ahi, Bhi1, acc1, 0, 0, 0);
        acc0 = __builtin_amdgcn_mfma_f32_16x16x32_bf16(Ahi, Blo0, acc0, 0, 0, 0);
        acc1 = __builtin_amdgcn_mfma_f32_16x16x32_bf16(Ahi, Blo1, acc1, 0, 0, 0);
        acc0 = __builtin_amdgcn_mfma_f32_16x16x32_bf16(Alo, Bhi0, acc0, 0, 0, 0);
        acc1 = __builtin_amdgcn_mfma_f32_16x16x32_bf16(Alo, Bhi1, acc1, 0, 0, 0);

        // C/D layout (verified): col = lane&15, row = (lane>>4)*4 + reg
        const int r0 = t * 16 + q * 4;
        float4 bv = *(const float4*)(b2 + r0);
        float bb[4] = {bv.x, bv.y, bv.z, bv.w};
#pragma unroll
        for (int r = 0; r < 4; ++r) {
            VT[r0 + r][cr]      = acc0[r] + bb[r];
            VT[r0 + r][cr + 16] = acc1[r] + bb[r];
        }
    }
    __syncthreads();

    // ---- routing (unchanged from round 3) ----
    const int cp_s = tid >> 3, cs = tid & 7;     // softmax/a-step mapping
    const int csa  = tid >> 4, asa = tid & 15;   // s-step mapping (tid == oc)

    float Vreg[NCP];
#pragma unroll
    for (int cp = 0; cp < NCP; ++cp) Vreg[cp] = VT[tid][cp];

    // r = 0: b == 0 -> softmax is uniform 1/16
    {
        float sv = 0.0f;
#pragma unroll
        for (int cp = 0; cp < NCP; ++cp) sv += Vreg[cp];
        sv *= 0.0625f;
        float sq = sv * sv;
        sq += __shfl_xor(sq, 1);
        sq += __shfl_xor(sq, 2);
        sq += __shfl_xor(sq, 4);
        sq += __shfl_xor(sq, 8);
        float vval = sq / (1.0f + sq) * sv / sqrtf(sq + EPSQ);
        vv[csa][asa] = vval;
        __syncthreads();
        float a0 = 0.0f, a1 = 0.0f;
#pragma unroll
        for (int qq = 0; qq < NASA; ++qq) {
            a0 = fmaf(VT[cs * 16 + qq][cp_s],       vv[cs][qq],     a0);
            a1 = fmaf(VT[(cs + 8) * 16 + qq][cp_s], vv[cs + 8][qq], a1);
        }
        br[cp_s][cs]     = a0;
        br[cp_s][cs + 8] = a1;
        __syncthreads();
    }

    for (int r = 1; r < 3; ++r) {
        float t0 = br[cp_s][cs], t1 = br[cp_s][cs + 8];
        float m = fmaxf(t0, t1);
        m = fmaxf(m, __shfl_xor(m, 1));
        m = fmaxf(m, __shfl_xor(m, 2));
        m = fmaxf(m, __shfl_xor(m, 4));
        float e0 = __expf(t0 - m), e1 = __expf(t1 - m);
        float ssum = e0 + e1;
        ssum += __shfl_xor(ssum, 1);
        ssum += __shfl_xor(ssum, 2);
        ssum += __shfl_xor(ssum, 4);
        float inv = 1.0f / ssum;
        cc[cp_s][cs]     = e0 * inv;
        cc[cp_s][cs + 8] = e1 * inv;
        __syncthreads();

        float sv = 0.0f;
#pragma unroll
        for (int cp = 0; cp < NCP; ++cp)
            sv = fmaf(cc[cp][csa], Vreg[cp], sv);
        float sq = sv * sv;
        sq += __shfl_xor(sq, 1);
        sq += __shfl_xor(sq, 2);
        sq += __shfl_xor(sq, 4);
        sq += __shfl_xor(sq, 8);
        float vval = sq / (1.0f + sq) * sv / sqrtf(sq + EPSQ);

        if (r == 2) {
            out[((size_t)b * NL + l) * NOC + tid] = vval;   // coalesced
        } else {
            vv[csa][asa] = vval;
            __syncthreads();
            float a0 = 0.0f, a1 = 0.0f;
#pragma unroll
            for (int qq = 0; qq < NASA; ++qq) {
                a0 = fmaf(VT[cs * 16 + qq][cp_s],       vv[cs][qq],     a0);
                a1 = fmaf(VT[(cs + 8) * 16 + qq][cp_s], vv[cs + 8][qq], a1);
            }
            br[cp_s][cs]     += a0;
            br[cp_s][cs + 8] += a1;
            __syncthreads();
        }
    }
}

extern "C" void kernel_launch(void* const* d_in, const int* in_sizes, int n_in,
                              void* d_out, int out_size, void* d_ws, size_t ws_size,
                              hipStream_t stream)
{
    const float* x  = (const float*)d_in[0];
    const float* w1 = (const float*)d_in[1];
    const float* b1 = (const float*)d_in[2];
    const float* w2 = (const float*)d_in[3];
    const float* b2 = (const float*)d_in[4];
    float* outp = (float*)d_out;
    float* ysq  = (float*)d_ws;            // 8*1024*256*4 = 8 MB scratch

    k1_conv1_squash<<<1024, 256, 0, stream>>>(x, w1, b1, ysq);
    k2_conv2_routing<<<NB * NL, 256, 0, stream>>>(ysq, w2, b2, outp);
}

// Round 5
// 150.083 us; speedup vs baseline: 1.3792x; 1.0335x over previous
//
#include <hip/hip_runtime.h>
#include <math.h>

#define NB   8
#define NK   64
#define NL   1024
#define NCP  32
#define NAP  8
#define NG2  9
#define NCSA 16
#define NASA 16
#define NG3  3
#define NOC  256      // = NCP*NAP = NCSA*NASA
#define EPSQ 1e-8f

typedef __bf16 bfv8 __attribute__((ext_vector_type(8)));
typedef float  f32x4 __attribute__((ext_vector_type(4)));

// ---------------- Kernel 1: conv1 (k=9, SAME) + bias + squash(ap=8) ----------
// block = 32 oc x 64 l. grid = 8 ocg * 16 ltile * 8 b = 1024 blocks.
// bounds(256,2): empirically this toolchain caps VGPR hard at higher args
// (R2: spill at 64; R4: 36-reg strangle) -> (256,2) restores load ILP.
// Output written as bf16 (hi plane) so k2's B fragments load with ZERO
// conversion VALU.
__global__ __launch_bounds__(256, 2) void k1_conv1_squash(
    const float* __restrict__ x, const float* __restrict__ w1,
    const float* __restrict__ b1, __bf16* __restrict__ ysq)
{
    __shared__ alignas(16) float xs[NK][72];   // 64 x 72 floats = 18 KB
    const int tid = threadIdx.x;
    const int bid = blockIdx.x;
    const int og = bid & 7;
    const int lt = (bid >> 3) & 15;
    const int b  = bid >> 7;
    const int l0 = lt * 64;

    const float* xb = x + (size_t)b * NK * NL;
    for (int idx = tid; idx < NK * 72; idx += 256) {
        int row = idx / 72, col = idx - row * 72;
        int l = l0 + col - 4;
        xs[row][col] = (l >= 0 && l < NL) ? xb[row * NL + l] : 0.0f;
    }

    const int ocl = tid & 31, lg = tid >> 5;
    const int oc  = og * 32 + ocl;

    float acc[8];
    {
        float bb = b1[oc];
#pragma unroll
        for (int i = 0; i < 8; ++i) acc[i] = bb;
    }
    __syncthreads();

    const float* wrow = w1 + (size_t)oc * (NK * NG2);
    for (int k4 = 0; k4 < NK; k4 += 4) {
        float wk[36];
        const float4* wp4 = (const float4*)(wrow + k4 * NG2);
#pragma unroll
        for (int q = 0; q < 9; ++q) {
            float4 v = wp4[q];
            wk[q*4+0]=v.x; wk[q*4+1]=v.y; wk[q*4+2]=v.z; wk[q*4+3]=v.w;
        }
#pragma unroll
        for (int kk = 0; kk < 4; ++kk) {
            float xr[16];
            const float4* xrow4 = (const float4*)(&xs[k4 + kk][lg * 8]);
#pragma unroll
            for (int q = 0; q < 4; ++q) {
                float4 v = xrow4[q];
                xr[q*4+0]=v.x; xr[q*4+1]=v.y; xr[q*4+2]=v.z; xr[q*4+3]=v.w;
            }
#pragma unroll
            for (int l = 0; l < 8; ++l)
#pragma unroll
                for (int g = 0; g < NG2; ++g)
                    acc[l] = fmaf(xr[l + g], wk[kk * NG2 + g], acc[l]);
        }
    }

    // squash over ap = 8 adjacent lanes; store bf16
#pragma unroll
    for (int l = 0; l < 8; ++l) {
        float sq = acc[l] * acc[l];
        sq += __shfl_xor(sq, 1);
        sq += __shfl_xor(sq, 2);
        sq += __shfl_xor(sq, 4);
        float val = sq / (1.0f + sq) * acc[l] / sqrtf(sq + EPSQ);
        ysq[((size_t)b * NL + l0 + lg * 8 + l) * NOC + oc] = (__bf16)val;
    }
}

// ---------------- Kernel 2: conv2 via MFMA (A split bf16, B bf16) + routing --
// grid = NB*NL = 8192 blocks, 256 threads = 4 waves.
// C[256 oc][32 cp] = W[256][24] * Ypatch[24][32], K padded to 32.
// A = w2 split hi/lo (in-kernel); B = ysq already bf16 -> raw 16B loads.
__device__ inline void a_frag(const float* p, bool ok, bfv8& hi, bfv8& lo)
{
    if (ok) {
        float4 a = ((const float4*)p)[0];
        float4 c = ((const float4*)p)[1];
        float v[8] = {a.x, a.y, a.z, a.w, c.x, c.y, c.z, c.w};
#pragma unroll
        for (int i = 0; i < 8; ++i) {
            __bf16 h = (__bf16)v[i];
            hi[i] = h;
            lo[i] = (__bf16)(v[i] - (float)h);
        }
    } else {
#pragma unroll
        for (int i = 0; i < 8; ++i) { hi[i] = (__bf16)0.0f; lo[i] = (__bf16)0.0f; }
    }
}

__global__ __launch_bounds__(256, 4) void k2_conv2_routing(
    const __bf16* __restrict__ ysq, const float* __restrict__ w2,
    const float* __restrict__ b2, float* __restrict__ out)
{
    __shared__ float VT[NOC][NCP + 1];      // V transposed [oc][cp], pad 33: 33.8 KB
    __shared__ float br[NCP][NCSA + 1];     // routing logits
    __shared__ float cc[NCP][NCSA + 1];     // softmax coeffs
    __shared__ float vv[NCSA][NASA + 1];    // squashed v        -> 39.2 KB total

    const int tid = threadIdx.x;
    const int bid = blockIdx.x;
    const int b = bid >> 10;
    const int l = bid & (NL - 1);

    const int lane = tid & 63;
    const int wv   = tid >> 6;          // wave 0..3
    const int q    = lane >> 4;         // k-chunk 0..3 (3 = zero pad)
    const int cr   = lane & 15;         // A-row / B-col within tile

    // ---- B fragments: raw bf16 loads from ysq patch ----
    const __bf16* ybase = ysq + ((size_t)b * NL + l) * NOC;
    const bool rowok = (q == 1) || (q == 0 && l > 0) || (q == 2 && l < NL - 1);
    bfv8 B0, B1;
    if (rowok) {
        B0 = *(const bfv8*)(ybase + (q - 1) * NOC + cr * 8);
        B1 = *(const bfv8*)(ybase + (q - 1) * NOC + (cr + 16) * 8);
    } else {
#pragma unroll
        for (int i = 0; i < 8; ++i) { B0[i] = (__bf16)0.0f; B1[i] = (__bf16)0.0f; }
    }

    // ---- 4 oc-tiles per wave: A frags + 4 MFMAs each ----
#pragma unroll
    for (int i = 0; i < 4; ++i) {
        const int t  = wv * 4 + i;
        const int oc = t * 16 + cr;
        bfv8 Ahi, Alo;
        a_frag(w2 + oc * 24 + q * 8, q < 3, Ahi, Alo);

        f32x4 acc0 = {0.f, 0.f, 0.f, 0.f};
        f32x4 acc1 = {0.f, 0.f, 0.f, 0.f};
        acc0 = __builtin_amdgcn_mfma_f32_16x16x32_bf16(Ahi, B0, acc0, 0, 0, 0);
        acc1 = __builtin_amdgcn_mfma_f32_16x16x32_bf16(Ahi, B1, acc1, 0, 0, 0);
        acc0 = __builtin_amdgcn_mfma_f32_16x16x32_bf16(Alo, B0, acc0, 0, 0, 0);
        acc1 = __builtin_amdgcn_mfma_f32_16x16x32_bf16(Alo, B1, acc1, 0, 0, 0);

        // C/D layout: col = lane&15, row = (lane>>4)*4 + reg
        const int r0 = t * 16 + q * 4;
        float4 bv = *(const float4*)(b2 + r0);
        float bb[4] = {bv.x, bv.y, bv.z, bv.w};
#pragma unroll
        for (int r = 0; r < 4; ++r) {
            VT[r0 + r][cr]      = acc0[r] + bb[r];
            VT[r0 + r][cr + 16] = acc1[r] + bb[r];
        }
    }
    __syncthreads();

    // ---- routing ----
    const int cp_s = tid >> 3, cs = tid & 7;
    const int csa  = tid >> 4, asa = tid & 15;

    float Vreg[NCP];
#pragma unroll
    for (int cp = 0; cp < NCP; ++cp) Vreg[cp] = VT[tid][cp];

    // r = 0: logits are 0 -> softmax uniform 1/16 (4-way partial sum)
    {
        float s0 = 0.f, s1 = 0.f, s2 = 0.f, s3 = 0.f;
#pragma unroll
        for (int cp = 0; cp < NCP; cp += 4) {
            s0 += Vreg[cp];     s1 += Vreg[cp + 1];
            s2 += Vreg[cp + 2]; s3 += Vreg[cp + 3];
        }
        float sv = ((s0 + s1) + (s2 + s3)) * 0.0625f;
        float sq = sv * sv;
        sq += __shfl_xor(sq, 1);
        sq += __shfl_xor(sq, 2);
        sq += __shfl_xor(sq, 4);
        sq += __shfl_xor(sq, 8);
        float vval = sq / (1.0f + sq) * sv / sqrtf(sq + EPSQ);
        vv[csa][asa] = vval;
        __syncthreads();
        float a0a = 0.f, a0b = 0.f, a1a = 0.f, a1b = 0.f;
#pragma unroll
        for (int qq = 0; qq < NASA; qq += 2) {
            a0a = fmaf(VT[cs * 16 + qq][cp_s],           vv[cs][qq],         a0a);
            a0b = fmaf(VT[cs * 16 + qq + 1][cp_s],       vv[cs][qq + 1],     a0b);
            a1a = fmaf(VT[(cs + 8) * 16 + qq][cp_s],     vv[cs + 8][qq],     a1a);
            a1b = fmaf(VT[(cs + 8) * 16 + qq + 1][cp_s], vv[cs + 8][qq + 1], a1b);
        }
        br[cp_s][cs]     = a0a + a0b;
        br[cp_s][cs + 8] = a1a + a1b;
        __syncthreads();
    }

    for (int r = 1; r < 3; ++r) {
        float t0 = br[cp_s][cs], t1 = br[cp_s][cs + 8];
        float m = fmaxf(t0, t1);
        m = fmaxf(m, __shfl_xor(m, 1));
        m = fmaxf(m, __shfl_xor(m, 2));
        m = fmaxf(m, __shfl_xor(m, 4));
        float e0 = __expf(t0 - m), e1 = __expf(t1 - m);
        float ssum = e0 + e1;
        ssum += __shfl_xor(ssum, 1);
        ssum += __shfl_xor(ssum, 2);
        ssum += __shfl_xor(ssum, 4);
        float inv = 1.0f / ssum;
        cc[cp_s][cs]     = e0 * inv;
        cc[cp_s][cs + 8] = e1 * inv;
        __syncthreads();

        // s-step: 4-way partial chains (fp can't be reassociated by compiler)
        float s0 = 0.f, s1 = 0.f, s2 = 0.f, s3 = 0.f;
#pragma unroll
        for (int cp = 0; cp < NCP; cp += 4) {
            s0 = fmaf(cc[cp][csa],     Vreg[cp],     s0);
            s1 = fmaf(cc[cp + 1][csa], Vreg[cp + 1], s1);
            s2 = fmaf(cc[cp + 2][csa], Vreg[cp + 2], s2);
            s3 = fmaf(cc[cp + 3][csa], Vreg[cp + 3], s3);
        }
        float sv = (s0 + s1) + (s2 + s3);
        float sq = sv * sv;
        sq += __shfl_xor(sq, 1);
        sq += __shfl_xor(sq, 2);
        sq += __shfl_xor(sq, 4);
        sq += __shfl_xor(sq, 8);
        float vval = sq / (1.0f + sq) * sv / sqrtf(sq + EPSQ);

        if (r == 2) {
            out[((size_t)b * NL + l) * NOC + tid] = vval;   // coalesced
        } else {
            vv[csa][asa] = vval;
            __syncthreads();
            float a0a = 0.f, a0b = 0.f, a1a = 0.f, a1b = 0.f;
#pragma unroll
            for (int qq = 0; qq < NASA; qq += 2) {
                a0a = fmaf(VT[cs * 16 + qq][cp_s],           vv[cs][qq],         a0a);
                a0b = fmaf(VT[cs * 16 + qq + 1][cp_s],       vv[cs][qq + 1],     a0b);
                a1a = fmaf(VT[(cs + 8) * 16 + qq][cp_s],     vv[cs + 8][qq],     a1a);
                a1b = fmaf(VT[(cs + 8) * 16 + qq + 1][cp_s], vv[cs + 8][qq + 1], a1b);
            }
            br[cp_s][cs]     += a0a + a0b;
            br[cp_s][cs + 8] += a1a + a1b;
            __syncthreads();
        }
    }
}

extern "C" void kernel_launch(void* const* d_in, const int* in_sizes, int n_in,
                              void* d_out, int out_size, void* d_ws, size_t ws_size,
                              hipStream_t stream)
{
    const float* x  = (const float*)d_in[0];
    const float* w1 = (const float*)d_in[1];
    const float* b1 = (const float*)d_in[2];
    const float* w2 = (const float*)d_in[3];
    const float* b2 = (const float*)d_in[4];
    float* outp = (float*)d_out;
    __bf16* ysq = (__bf16*)d_ws;           // 8*1024*256*2 = 4 MB scratch

    k1_conv1_squash<<<1024, 256, 0, stream>>>(x, w1, b1, ysq);
    k2_conv2_routing<<<NB * NL, 256, 0, stream>>>(ysq, w2, b2, outp);
}

// Round 6
// 94.107 us; speedup vs baseline: 2.1995x; 1.5948x over previous
//
#include <hip/hip_runtime.h>
#include <math.h>

#define NB   8
#define NK   64
#define NL   1024
#define NCP  32
#define NAP  8
#define NG2  9
#define NCSA 16
#define NASA 16
#define NG3  3
#define NOC  256      // = NCP*NAP = NCSA*NASA
#define EPSQ 1e-8f

typedef __bf16 bfv8 __attribute__((ext_vector_type(8)));
typedef float  f32x4 __attribute__((ext_vector_type(4)));

static __device__ inline unsigned short bfbits(float v) {
    __bf16 h = (__bf16)v;
    return __builtin_bit_cast(unsigned short, h);
}
static __device__ inline unsigned int bfpack2(float v0, float v1) {
    return (unsigned int)bfbits(v0) | ((unsigned int)bfbits(v1) << 16);
}
static __device__ inline unsigned int bfpack2lo(float v0, float v1) {
    float h0 = (float)(__bf16)v0, h1 = (float)(__bf16)v1;
    return (unsigned int)bfbits(v0 - h0) | ((unsigned int)bfbits(v1 - h1) << 16);
}

// ---------------- k0: prep — transpose/split operands to bf16 hi/lo planes ---
// blocks 0..127   : xT[b][l][kk] hi/lo   (LDS-transposed, coalesced both sides)
// blocks 128..415 : w1T[g][oc][kk] hi/lo
// block  416      : w2 hi/lo
__global__ __launch_bounds__(256) void k0_prep(
    const float* __restrict__ x, const float* __restrict__ w1,
    const float* __restrict__ w2,
    __bf16* __restrict__ xThi, __bf16* __restrict__ xTlo,
    __bf16* __restrict__ w1Thi, __bf16* __restrict__ w1Tlo,
    __bf16* __restrict__ w2hi, __bf16* __restrict__ w2lo)
{
    const int tid = threadIdx.x;
    const int bid = blockIdx.x;
    if (bid < 128) {
        __shared__ float tile[64][65];
        const int b = bid >> 4, l0 = (bid & 15) * 64;
        const float* xb = x + (size_t)b * NK * NL;
        const int lcol = tid & 63, kr = tid >> 6;
#pragma unroll
        for (int pass = 0; pass < 16; ++pass) {
            int kk = pass * 4 + kr;
            tile[lcol][kk] = xb[(size_t)kk * NL + l0 + lcol];
        }
        __syncthreads();
        const int lr = tid >> 5, pc = tid & 31;
#pragma unroll
        for (int pass = 0; pass < 8; ++pass) {
            int ll = pass * 8 + lr;
            float v0 = tile[ll][pc * 2], v1 = tile[ll][pc * 2 + 1];
            size_t base = ((size_t)b * NL + l0 + ll) * 64 + pc * 2;
            *(unsigned int*)(xThi + base) = bfpack2(v0, v1);
            *(unsigned int*)(xTlo + base) = bfpack2lo(v0, v1);
        }
    } else if (bid < 128 + 288) {
        // w1[oc][kk][g] -> w1T[g][oc][kk]; 9*256*32 pair-jobs
        int idx = (bid - 128) * 256 + tid;
        int kp = idx & 31, rest = idx >> 5;
        int oc = rest & 255, g = rest >> 8;
        float v0 = w1[(size_t)oc * 576 + (kp * 2) * NG2 + g];
        float v1 = w1[(size_t)oc * 576 + (kp * 2 + 1) * NG2 + g];
        size_t base = ((size_t)(g * NOC + oc)) * 64 + kp * 2;
        *(unsigned int*)(w1Thi + base) = bfpack2(v0, v1);
        *(unsigned int*)(w1Tlo + base) = bfpack2lo(v0, v1);
    } else {
        for (int i = tid; i < NOC * 24; i += 256) {
            float v = w2[i];
            float h = (float)(__bf16)v;
            w2hi[i] = (__bf16)v;
            w2lo[i] = (__bf16)(v - h);
        }
    }
}

// ---------------- k1: conv1 via MFMA (9 shifted K=64 GEMMs) + squash ---------
// block = [64 oc x 64 l], 4 waves; wave = 1 octile(16 oc) x 4 ltiles(16 l).
// grid = 4 ocb * 16 lb * 8 b = 512 blocks.
// B-frags from LDS x-patch (72 rows x 64 kk bf16, hi/lo), 16B-granule
// XOR-swizzled by row&7 (row stride = 128B -> would alias banks otherwise).
__global__ __launch_bounds__(256) void k1_mfma(
    const __bf16* __restrict__ xThi, const __bf16* __restrict__ xTlo,
    const __bf16* __restrict__ w1Thi, const __bf16* __restrict__ w1Tlo,
    const float* __restrict__ b1, __bf16* __restrict__ ysq)
{
    __shared__ alignas(16) __bf16 xph[72][64];
    __shared__ alignas(16) __bf16 xpl[72][64];
    const int tid = threadIdx.x;
    const int bid = blockIdx.x;
    const int ocb = bid & 3;
    const int lb  = (bid >> 2) & 15;
    const int b   = bid >> 6;
    const int l0  = lb * 64;

    // stage x patch, swizzled
    {
        const int row0 = tid >> 3, seg = tid & 7;
#pragma unroll
        for (int p = 0; p < 3; ++p) {
            int row = p * 32 + row0;
            if (row < 72) {
                int l = l0 - 4 + row;
                int sw = seg ^ (row & 7);
                uint4 vh = {0u,0u,0u,0u}, vl = {0u,0u,0u,0u};
                if (l >= 0 && l < NL) {
                    size_t off = ((size_t)b * NL + l) * 64 + seg * 8;
                    vh = *(const uint4*)(xThi + off);
                    vl = *(const uint4*)(xTlo + off);
                }
                *(uint4*)(&xph[row][sw * 8]) = vh;
                *(uint4*)(&xpl[row][sw * 8]) = vl;
            }
        }
    }
    __syncthreads();

    const int lane = tid & 63, wv = tid >> 6;
    const int qq = lane >> 4, cr = lane & 15;
    const int oco = ocb * 64 + wv * 16;     // wave's octile base

    f32x4 acc[4];
#pragma unroll
    for (int lt = 0; lt < 4; ++lt) acc[lt] = (f32x4){0.f, 0.f, 0.f, 0.f};

    for (int g = 0; g < NG2; ++g) {
#pragma unroll
        for (int s = 0; s < 2; ++s) {
            size_t aoff = ((size_t)(g * NOC + oco + cr)) * 64 + s * 32 + qq * 8;
            bfv8 Ahi = *(const bfv8*)(w1Thi + aoff);
            bfv8 Alo = *(const bfv8*)(w1Tlo + aoff);
#pragma unroll
            for (int lt = 0; lt < 4; ++lt) {
                int row = lt * 16 + cr + g;
                int gr = (s * 4 + qq) ^ (row & 7);
                bfv8 Bhi = *(const bfv8*)(&xph[row][gr * 8]);
                bfv8 Blo = *(const bfv8*)(&xpl[row][gr * 8]);
                acc[lt] = __builtin_amdgcn_mfma_f32_16x16x32_bf16(Ahi, Bhi, acc[lt], 0, 0, 0);
                acc[lt] = __builtin_amdgcn_mfma_f32_16x16x32_bf16(Alo, Bhi, acc[lt], 0, 0, 0);
                acc[lt] = __builtin_amdgcn_mfma_f32_16x16x32_bf16(Ahi, Blo, acc[lt], 0, 0, 0);
            }
        }
    }

    // epilogue: bias + squash over oc-octets (qq pairs via shfl_xor 16), bf16 out
    const float4 bv = *(const float4*)(b1 + oco + qq * 4);
#pragma unroll
    for (int lt = 0; lt < 4; ++lt) {
        float v0 = acc[lt][0] + bv.x, v1 = acc[lt][1] + bv.y;
        float v2 = acc[lt][2] + bv.z, v3 = acc[lt][3] + bv.w;
        float s = v0*v0 + v1*v1 + v2*v2 + v3*v3;
        float s8 = s + __shfl_xor(s, 16);
        float scale = s8 / (1.0f + s8) / sqrtf(s8 + EPSQ);
        uint2 st;
        st.x = bfpack2(v0 * scale, v1 * scale);
        st.y = bfpack2(v2 * scale, v3 * scale);
        int l = l0 + lt * 16 + cr;
        *(uint2*)(ysq + ((size_t)b * NL + l) * NOC + oco + qq * 4) = st;
    }
}

// ---------------- k2: conv2 via MFMA (pre-split A, bf16 B) + routing ---------
__global__ __launch_bounds__(256, 4) void k2_conv2_routing(
    const __bf16* __restrict__ ysq,
    const __bf16* __restrict__ w2hi, const __bf16* __restrict__ w2lo,
    const float* __restrict__ b2, float* __restrict__ out)
{
    __shared__ float VT[NOC][NCP + 1];      // V transposed [oc][cp], pad 33
    __shared__ float br[NCP][NCSA + 1];
    __shared__ float cc[NCP][NCSA + 1];
    __shared__ float vv[NCSA][NASA + 1];

    const int tid = threadIdx.x;
    const int bid = blockIdx.x;
    const int b = bid >> 10;
    const int l = bid & (NL - 1);

    const int lane = tid & 63;
    const int wv   = tid >> 6;
    const int q    = lane >> 4;
    const int cr   = lane & 15;

    const __bf16* ybase = ysq + ((size_t)b * NL + l) * NOC;
    const bool rowok = (q == 1) || (q == 0 && l > 0) || (q == 2 && l < NL - 1);
    bfv8 B0, B1;
    if (rowok) {
        B0 = *(const bfv8*)(ybase + (q - 1) * NOC + cr * 8);
        B1 = *(const bfv8*)(ybase + (q - 1) * NOC + (cr + 16) * 8);
    } else {
#pragma unroll
        for (int i = 0; i < 8; ++i) { B0[i] = (__bf16)0.0f; B1[i] = (__bf16)0.0f; }
    }

#pragma unroll
    for (int i = 0; i < 4; ++i) {
        const int t  = wv * 4 + i;
        const int oc = t * 16 + cr;
        bfv8 Ahi, Alo;
        if (q < 3) {
            Ahi = *(const bfv8*)(w2hi + oc * 24 + q * 8);
            Alo = *(const bfv8*)(w2lo + oc * 24 + q * 8);
        } else {
#pragma unroll
            for (int j = 0; j < 8; ++j) { Ahi[j] = (__bf16)0.0f; Alo[j] = (__bf16)0.0f; }
        }

        f32x4 acc0 = {0.f, 0.f, 0.f, 0.f};
        f32x4 acc1 = {0.f, 0.f, 0.f, 0.f};
        acc0 = __builtin_amdgcn_mfma_f32_16x16x32_bf16(Ahi, B0, acc0, 0, 0, 0);
        acc1 = __builtin_amdgcn_mfma_f32_16x16x32_bf16(Ahi, B1, acc1, 0, 0, 0);
        acc0 = __builtin_amdgcn_mfma_f32_16x16x32_bf16(Alo, B0, acc0, 0, 0, 0);
        acc1 = __builtin_amdgcn_mfma_f32_16x16x32_bf16(Alo, B1, acc1, 0, 0, 0);

        const int r0 = t * 16 + q * 4;
        float4 bvv = *(const float4*)(b2 + r0);
        float bb[4] = {bvv.x, bvv.y, bvv.z, bvv.w};
#pragma unroll
        for (int r = 0; r < 4; ++r) {
            VT[r0 + r][cr]      = acc0[r] + bb[r];
            VT[r0 + r][cr + 16] = acc1[r] + bb[r];
        }
    }
    __syncthreads();

    // ---- routing ----
    const int cp_s = tid >> 3, cs = tid & 7;
    const int csa  = tid >> 4, asa = tid & 15;

    float Vreg[NCP];
#pragma unroll
    for (int cp = 0; cp < NCP; ++cp) Vreg[cp] = VT[tid][cp];

    // r = 0: logits 0 -> uniform softmax
    {
        float s0 = 0.f, s1 = 0.f, s2 = 0.f, s3 = 0.f;
#pragma unroll
        for (int cp = 0; cp < NCP; cp += 4) {
            s0 += Vreg[cp];     s1 += Vreg[cp + 1];
            s2 += Vreg[cp + 2]; s3 += Vreg[cp + 3];
        }
        float sv = ((s0 + s1) + (s2 + s3)) * 0.0625f;
        float sq = sv * sv;
        sq += __shfl_xor(sq, 1);
        sq += __shfl_xor(sq, 2);
        sq += __shfl_xor(sq, 4);
        sq += __shfl_xor(sq, 8);
        float vval = sq / (1.0f + sq) * sv / sqrtf(sq + EPSQ);
        vv[csa][asa] = vval;
        __syncthreads();
        float a0a = 0.f, a0b = 0.f, a1a = 0.f, a1b = 0.f;
#pragma unroll
        for (int qq2 = 0; qq2 < NASA; qq2 += 2) {
            a0a = fmaf(VT[cs * 16 + qq2][cp_s],           vv[cs][qq2],         a0a);
            a0b = fmaf(VT[cs * 16 + qq2 + 1][cp_s],       vv[cs][qq2 + 1],     a0b);
            a1a = fmaf(VT[(cs + 8) * 16 + qq2][cp_s],     vv[cs + 8][qq2],     a1a);
            a1b = fmaf(VT[(cs + 8) * 16 + qq2 + 1][cp_s], vv[cs + 8][qq2 + 1], a1b);
        }
        br[cp_s][cs]     = a0a + a0b;
        br[cp_s][cs + 8] = a1a + a1b;
        __syncthreads();
    }

    for (int r = 1; r < 3; ++r) {
        float t0 = br[cp_s][cs], t1 = br[cp_s][cs + 8];
        float m = fmaxf(t0, t1);
        m = fmaxf(m, __shfl_xor(m, 1));
        m = fmaxf(m, __shfl_xor(m, 2));
        m = fmaxf(m, __shfl_xor(m, 4));
        float e0 = __expf(t0 - m), e1 = __expf(t1 - m);
        float ssum = e0 + e1;
        ssum += __shfl_xor(ssum, 1);
        ssum += __shfl_xor(ssum, 2);
        ssum += __shfl_xor(ssum, 4);
        float inv = 1.0f / ssum;
        cc[cp_s][cs]     = e0 * inv;
        cc[cp_s][cs + 8] = e1 * inv;
        __syncthreads();

        float s0 = 0.f, s1 = 0.f, s2 = 0.f, s3 = 0.f;
#pragma unroll
        for (int cp = 0; cp < NCP; cp += 4) {
            s0 = fmaf(cc[cp][csa],     Vreg[cp],     s0);
            s1 = fmaf(cc[cp + 1][csa], Vreg[cp + 1], s1);
            s2 = fmaf(cc[cp + 2][csa], Vreg[cp + 2], s2);
            s3 = fmaf(cc[cp + 3][csa], Vreg[cp + 3], s3);
        }
        float sv = (s0 + s1) + (s2 + s3);
        float sq = sv * sv;
        sq += __shfl_xor(sq, 1);
        sq += __shfl_xor(sq, 2);
        sq += __shfl_xor(sq, 4);
        sq += __shfl_xor(sq, 8);
        float vval = sq / (1.0f + sq) * sv / sqrtf(sq + EPSQ);

        if (r == 2) {
            out[((size_t)b * NL + l) * NOC + tid] = vval;
        } else {
            vv[csa][asa] = vval;
            __syncthreads();
            float a0a = 0.f, a0b = 0.f, a1a = 0.f, a1b = 0.f;
#pragma unroll
            for (int qq2 = 0; qq2 < NASA; qq2 += 2) {
                a0a = fmaf(VT[cs * 16 + qq2][cp_s],           vv[cs][qq2],         a0a);
                a0b = fmaf(VT[cs * 16 + qq2 + 1][cp_s],       vv[cs][qq2 + 1],     a0b);
                a1a = fmaf(VT[(cs + 8) * 16 + qq2][cp_s],     vv[cs + 8][qq2],     a1a);
                a1b = fmaf(VT[(cs + 8) * 16 + qq2 + 1][cp_s], vv[cs + 8][qq2 + 1], a1b);
            }
            br[cp_s][cs]     += a0a + a0b;
            br[cp_s][cs + 8] += a1a + a1b;
            __syncthreads();
        }
    }
}

extern "C" void kernel_launch(void* const* d_in, const int* in_sizes, int n_in,
                              void* d_out, int out_size, void* d_ws, size_t ws_size,
                              hipStream_t stream)
{
    const float* x  = (const float*)d_in[0];
    const float* w1 = (const float*)d_in[1];
    const float* b1 = (const float*)d_in[2];
    const float* w2 = (const float*)d_in[3];
    const float* b2 = (const float*)d_in[4];
    float* outp = (float*)d_out;

    char* ws = (char*)d_ws;
    __bf16* ysq   = (__bf16*)(ws);                 // 8*1024*256*2     = 4,194,304
    __bf16* xThi  = (__bf16*)(ws + 4194304);       // 8*1024*64*2      = 1,048,576
    __bf16* xTlo  = (__bf16*)(ws + 5242880);       //                  = 1,048,576
    __bf16* w1Thi = (__bf16*)(ws + 6291456);       // 9*256*64*2       =   294,912
    __bf16* w1Tlo = (__bf16*)(ws + 6586368);       //                  =   294,912
    __bf16* w2hi  = (__bf16*)(ws + 6881280);       // 256*24*2         =    12,288
    __bf16* w2lo  = (__bf16*)(ws + 6893568);       // total 6,905,856 B (< 8 MB ws)

    k0_prep<<<417, 256, 0, stream>>>(x, w1, w2, xThi, xTlo, w1Thi, w1Tlo, w2hi, w2lo);
    k1_mfma<<<512, 256, 0, stream>>>(xThi, xTlo, w1Thi, w1Tlo, b1, ysq);
    k2_conv2_routing<<<NB * NL, 256, 0, stream>>>(ysq, w2hi, w2lo, b2, outp);
}

// Round 7
// 70.531 us; speedup vs baseline: 2.9348x; 1.3343x over previous
//
#include <hip/hip_runtime.h>
#include <math.h>

#define NB   8
#define NK   64
#define NL   1024
#define NCP  32
#define NAP  8
#define NG2  9
#define NCSA 16
#define NASA 16
#define NG3  3
#define NOC  256      // = NCP*NAP = NCSA*NASA
#define EPSQ 1e-8f
#define VBS  258      // Vb row stride in bf16 elems (256 + 2 pad)

typedef __bf16 bfv8 __attribute__((ext_vector_type(8)));
typedef float  f32x4 __attribute__((ext_vector_type(4)));

static __device__ inline unsigned short bfbits(float v) {
    __bf16 h = (__bf16)v;
    return __builtin_bit_cast(unsigned short, h);
}
static __device__ inline unsigned int bfpack2(float v0, float v1) {
    return (unsigned int)bfbits(v0) | ((unsigned int)bfbits(v1) << 16);
}
static __device__ inline unsigned int bfpack2lo(float v0, float v1) {
    float h0 = (float)(__bf16)v0, h1 = (float)(__bf16)v1;
    return (unsigned int)bfbits(v0 - h0) | ((unsigned int)bfbits(v1 - h1) << 16);
}

// ---------------- k0: prep — transpose/split operands to bf16 hi/lo planes ---
__global__ __launch_bounds__(256) void k0_prep(
    const float* __restrict__ x, const float* __restrict__ w1,
    const float* __restrict__ w2,
    __bf16* __restrict__ xThi, __bf16* __restrict__ xTlo,
    __bf16* __restrict__ w1Thi, __bf16* __restrict__ w1Tlo,
    __bf16* __restrict__ w2hi, __bf16* __restrict__ w2lo)
{
    const int tid = threadIdx.x;
    const int bid = blockIdx.x;
    if (bid < 128) {
        __shared__ float tile[64][65];
        const int b = bid >> 4, l0 = (bid & 15) * 64;
        const float* xb = x + (size_t)b * NK * NL;
        const int lcol = tid & 63, kr = tid >> 6;
#pragma unroll
        for (int pass = 0; pass < 16; ++pass) {
            int kk = pass * 4 + kr;
            tile[lcol][kk] = xb[(size_t)kk * NL + l0 + lcol];
        }
        __syncthreads();
        const int lr = tid >> 5, pc = tid & 31;
#pragma unroll
        for (int pass = 0; pass < 8; ++pass) {
            int ll = pass * 8 + lr;
            float v0 = tile[ll][pc * 2], v1 = tile[ll][pc * 2 + 1];
            size_t base = ((size_t)b * NL + l0 + ll) * 64 + pc * 2;
            *(unsigned int*)(xThi + base) = bfpack2(v0, v1);
            *(unsigned int*)(xTlo + base) = bfpack2lo(v0, v1);
        }
    } else if (bid < 128 + 288) {
        int idx = (bid - 128) * 256 + tid;
        int kp = idx & 31, rest = idx >> 5;
        int oc = rest & 255, g = rest >> 8;
        float v0 = w1[(size_t)oc * 576 + (kp * 2) * NG2 + g];
        float v1 = w1[(size_t)oc * 576 + (kp * 2 + 1) * NG2 + g];
        size_t base = ((size_t)(g * NOC + oc)) * 64 + kp * 2;
        *(unsigned int*)(w1Thi + base) = bfpack2(v0, v1);
        *(unsigned int*)(w1Tlo + base) = bfpack2lo(v0, v1);
    } else {
        for (int i = tid; i < NOC * 24; i += 256) {
            float v = w2[i];
            float h = (float)(__bf16)v;
            w2hi[i] = (__bf16)v;
            w2lo[i] = (__bf16)(v - h);
        }
    }
}

// ---------------- k1: conv1 via MFMA (9 shifted K=64 GEMMs) + squash ---------
__global__ __launch_bounds__(256) void k1_mfma(
    const __bf16* __restrict__ xThi, const __bf16* __restrict__ xTlo,
    const __bf16* __restrict__ w1Thi, const __bf16* __restrict__ w1Tlo,
    const float* __restrict__ b1, __bf16* __restrict__ ysq)
{
    __shared__ alignas(16) __bf16 xph[72][64];
    __shared__ alignas(16) __bf16 xpl[72][64];
    const int tid = threadIdx.x;
    const int bid = blockIdx.x;
    const int ocb = bid & 3;
    const int lb  = (bid >> 2) & 15;
    const int b   = bid >> 6;
    const int l0  = lb * 64;

    {
        const int row0 = tid >> 3, seg = tid & 7;
#pragma unroll
        for (int p = 0; p < 3; ++p) {
            int row = p * 32 + row0;
            if (row < 72) {
                int l = l0 - 4 + row;
                int sw = seg ^ (row & 7);
                uint4 vh = {0u,0u,0u,0u}, vl = {0u,0u,0u,0u};
                if (l >= 0 && l < NL) {
                    size_t off = ((size_t)b * NL + l) * 64 + seg * 8;
                    vh = *(const uint4*)(xThi + off);
                    vl = *(const uint4*)(xTlo + off);
                }
                *(uint4*)(&xph[row][sw * 8]) = vh;
                *(uint4*)(&xpl[row][sw * 8]) = vl;
            }
        }
    }
    __syncthreads();

    const int lane = tid & 63, wv = tid >> 6;
    const int qq = lane >> 4, cr = lane & 15;
    const int oco = ocb * 64 + wv * 16;

    f32x4 acc[4];
#pragma unroll
    for (int lt = 0; lt < 4; ++lt) acc[lt] = (f32x4){0.f, 0.f, 0.f, 0.f};

    for (int g = 0; g < NG2; ++g) {
#pragma unroll
        for (int s = 0; s < 2; ++s) {
            size_t aoff = ((size_t)(g * NOC + oco + cr)) * 64 + s * 32 + qq * 8;
            bfv8 Ahi = *(const bfv8*)(w1Thi + aoff);
            bfv8 Alo = *(const bfv8*)(w1Tlo + aoff);
#pragma unroll
            for (int lt = 0; lt < 4; ++lt) {
                int row = lt * 16 + cr + g;
                int gr = (s * 4 + qq) ^ (row & 7);
                bfv8 Bhi = *(const bfv8*)(&xph[row][gr * 8]);
                bfv8 Blo = *(const bfv8*)(&xpl[row][gr * 8]);
                acc[lt] = __builtin_amdgcn_mfma_f32_16x16x32_bf16(Ahi, Bhi, acc[lt], 0, 0, 0);
                acc[lt] = __builtin_amdgcn_mfma_f32_16x16x32_bf16(Alo, Bhi, acc[lt], 0, 0, 0);
                acc[lt] = __builtin_amdgcn_mfma_f32_16x16x32_bf16(Ahi, Blo, acc[lt], 0, 0, 0);
            }
        }
    }

    const float4 bv = *(const float4*)(b1 + oco + qq * 4);
#pragma unroll
    for (int lt = 0; lt < 4; ++lt) {
        float v0 = acc[lt][0] + bv.x, v1 = acc[lt][1] + bv.y;
        float v2 = acc[lt][2] + bv.z, v3 = acc[lt][3] + bv.w;
        float s = v0*v0 + v1*v1 + v2*v2 + v3*v3;
        float s8 = s + __shfl_xor(s, 16);
        float scale = s8 / (1.0f + s8) / sqrtf(s8 + EPSQ);
        uint2 st;
        st.x = bfpack2(v0 * scale, v1 * scale);
        st.y = bfpack2(v2 * scale, v3 * scale);
        int l = l0 + lt * 16 + cr;
        *(uint2*)(ysq + ((size_t)b * NL + l) * NOC + oco + qq * 4) = st;
    }
}

// ---------------- k2: conv2 via MFMA + routing (bf16 V in LDS, 7 blocks/CU) --
// Vb[cp][oc] bf16, row stride 258:
//  - V-compute writes: packed b32 pairs (oc-consecutive)
//  - Vreg hoist Vb[cp][tid]: bank (cp + tid/2) -> 2-way, free
//  - a-step (cp_m=tid&31, cs_m=tid>>5): 8 consecutive b32, bank cp_m+8cs_m+j
//    -> exactly 2 lanes/bank, free (was 4-way on 64 reads with old mapping)
__global__ __launch_bounds__(256, 4) void k2_conv2_routing(
    const __bf16* __restrict__ ysq,
    const __bf16* __restrict__ w2hi, const __bf16* __restrict__ w2lo,
    const float* __restrict__ b2, float* __restrict__ out)
{
    __shared__ alignas(16) __bf16 Vb[NCP * VBS];   // 16.1 KB
    __shared__ float br[NCP][NCSA + 1];            // 2.1 KB
    __shared__ float cc[NCP][NCSA + 1];            // 2.1 KB
    __shared__ float vv[NCSA][NASA + 1];           // 1.1 KB -> 21.95 KB total

    const int tid = threadIdx.x;
    const int bid = blockIdx.x;
    const int b = bid >> 10;
    const int l = bid & (NL - 1);

    const int lane = tid & 63;
    const int wv   = tid >> 6;
    const int q    = lane >> 4;
    const int cr   = lane & 15;

    const __bf16* ybase = ysq + ((size_t)b * NL + l) * NOC;
    const bool rowok = (q == 1) || (q == 0 && l > 0) || (q == 2 && l < NL - 1);
    bfv8 B0, B1;
    if (rowok) {
        B0 = *(const bfv8*)(ybase + (q - 1) * NOC + cr * 8);
        B1 = *(const bfv8*)(ybase + (q - 1) * NOC + (cr + 16) * 8);
    } else {
#pragma unroll
        for (int i = 0; i < 8; ++i) { B0[i] = (__bf16)0.0f; B1[i] = (__bf16)0.0f; }
    }

#pragma unroll
    for (int i = 0; i < 4; ++i) {
        const int t  = wv * 4 + i;
        const int oc = t * 16 + cr;
        bfv8 Ahi, Alo;
        if (q < 3) {
            Ahi = *(const bfv8*)(w2hi + oc * 24 + q * 8);
            Alo = *(const bfv8*)(w2lo + oc * 24 + q * 8);
        } else {
#pragma unroll
            for (int j = 0; j < 8; ++j) { Ahi[j] = (__bf16)0.0f; Alo[j] = (__bf16)0.0f; }
        }

        f32x4 acc0 = {0.f, 0.f, 0.f, 0.f};
        f32x4 acc1 = {0.f, 0.f, 0.f, 0.f};
        acc0 = __builtin_amdgcn_mfma_f32_16x16x32_bf16(Ahi, B0, acc0, 0, 0, 0);
        acc1 = __builtin_amdgcn_mfma_f32_16x16x32_bf16(Ahi, B1, acc1, 0, 0, 0);
        acc0 = __builtin_amdgcn_mfma_f32_16x16x32_bf16(Alo, B0, acc0, 0, 0, 0);
        acc1 = __builtin_amdgcn_mfma_f32_16x16x32_bf16(Alo, B1, acc1, 0, 0, 0);

        // C/D layout: col(cp) = lane&15, row(oc) = q*4 + reg (+ t*16)
        const int r0 = t * 16 + q * 4;
        float4 bvv = *(const float4*)(b2 + r0);
        // rows oc=r0..r0+3 are consecutive in Vb's oc dim -> packed b32 writes
        *(unsigned int*)(&Vb[cr * VBS + r0])            = bfpack2(acc0[0] + bvv.x, acc0[1] + bvv.y);
        *(unsigned int*)(&Vb[cr * VBS + r0 + 2])        = bfpack2(acc0[2] + bvv.z, acc0[3] + bvv.w);
        *(unsigned int*)(&Vb[(cr + 16) * VBS + r0])     = bfpack2(acc1[0] + bvv.x, acc1[1] + bvv.y);
        *(unsigned int*)(&Vb[(cr + 16) * VBS + r0 + 2]) = bfpack2(acc1[2] + bvv.z, acc1[3] + bvv.w);
    }
    __syncthreads();

    // ---- routing ----
    const int cp_s = tid >> 3, cs = tid & 7;     // softmax mapping (8-lane groups)
    const int csa  = tid >> 4, asa = tid & 15;   // s-step mapping (tid == oc)
    const int cp_m = tid & 31, cs_m = tid >> 5;  // a-step mapping (conflict-free)

    float Vreg[NCP];
#pragma unroll
    for (int cp = 0; cp < NCP; ++cp) Vreg[cp] = (float)Vb[cp * VBS + tid];

    const unsigned int* arow0 = (const unsigned int*)(&Vb[cp_m * VBS + cs_m * 16]);
    const unsigned int* arow1 = (const unsigned int*)(&Vb[cp_m * VBS + (cs_m + 8) * 16]);

    // r = 0: logits 0 -> uniform softmax
    {
        float s0 = 0.f, s1 = 0.f, s2 = 0.f, s3 = 0.f;
#pragma unroll
        for (int cp = 0; cp < NCP; cp += 4) {
            s0 += Vreg[cp];     s1 += Vreg[cp + 1];
            s2 += Vreg[cp + 2]; s3 += Vreg[cp + 3];
        }
        float sv = ((s0 + s1) + (s2 + s3)) * 0.0625f;
        float sq = sv * sv;
        sq += __shfl_xor(sq, 1);
        sq += __shfl_xor(sq, 2);
        sq += __shfl_xor(sq, 4);
        sq += __shfl_xor(sq, 8);
        float vval = sq / (1.0f + sq) * sv / sqrtf(sq + EPSQ);
        vv[csa][asa] = vval;
        __syncthreads();
        float a0a = 0.f, a0b = 0.f, a1a = 0.f, a1b = 0.f;
#pragma unroll
        for (int j = 0; j < 8; ++j) {
            unsigned int d0 = arow0[j], d1 = arow1[j];
            a0a = fmaf(__builtin_bit_cast(float, d0 << 16),          vv[cs_m][2*j],       a0a);
            a0b = fmaf(__builtin_bit_cast(float, d0 & 0xFFFF0000u),  vv[cs_m][2*j + 1],   a0b);
            a1a = fmaf(__builtin_bit_cast(float, d1 << 16),          vv[cs_m+8][2*j],     a1a);
            a1b = fmaf(__builtin_bit_cast(float, d1 & 0xFFFF0000u),  vv[cs_m+8][2*j + 1], a1b);
        }
        br[cp_m][cs_m]     = a0a + a0b;
        br[cp_m][cs_m + 8] = a1a + a1b;
        __syncthreads();
    }

    for (int r = 1; r < 3; ++r) {
        float t0 = br[cp_s][cs], t1 = br[cp_s][cs + 8];
        float m = fmaxf(t0, t1);
        m = fmaxf(m, __shfl_xor(m, 1));
        m = fmaxf(m, __shfl_xor(m, 2));
        m = fmaxf(m, __shfl_xor(m, 4));
        float e0 = __expf(t0 - m), e1 = __expf(t1 - m);
        float ssum = e0 + e1;
        ssum += __shfl_xor(ssum, 1);
        ssum += __shfl_xor(ssum, 2);
        ssum += __shfl_xor(ssum, 4);
        float inv = 1.0f / ssum;
        cc[cp_s][cs]     = e0 * inv;
        cc[cp_s][cs + 8] = e1 * inv;
        __syncthreads();

        float s0 = 0.f, s1 = 0.f, s2 = 0.f, s3 = 0.f;
#pragma unroll
        for (int cp = 0; cp < NCP; cp += 4) {
            s0 = fmaf(cc[cp][csa],     Vreg[cp],     s0);
            s1 = fmaf(cc[cp + 1][csa], Vreg[cp + 1], s1);
            s2 = fmaf(cc[cp + 2][csa], Vreg[cp + 2], s2);
            s3 = fmaf(cc[cp + 3][csa], Vreg[cp + 3], s3);
        }
        float sv = (s0 + s1) + (s2 + s3);
        float sq = sv * sv;
        sq += __shfl_xor(sq, 1);
        sq += __shfl_xor(sq, 2);
        sq += __shfl_xor(sq, 4);
        sq += __shfl_xor(sq, 8);
        float vval = sq / (1.0f + sq) * sv / sqrtf(sq + EPSQ);

        if (r == 2) {
            out[((size_t)b * NL + l) * NOC + tid] = vval;
        } else {
            vv[csa][asa] = vval;
            __syncthreads();
            float a0a = 0.f, a0b = 0.f, a1a = 0.f, a1b = 0.f;
#pragma unroll
            for (int j = 0; j < 8; ++j) {
                unsigned int d0 = arow0[j], d1 = arow1[j];
                a0a = fmaf(__builtin_bit_cast(float, d0 << 16),          vv[cs_m][2*j],       a0a);
                a0b = fmaf(__builtin_bit_cast(float, d0 & 0xFFFF0000u),  vv[cs_m][2*j + 1],   a0b);
                a1a = fmaf(__builtin_bit_cast(float, d1 << 16),          vv[cs_m+8][2*j],     a1a);
                a1b = fmaf(__builtin_bit_cast(float, d1 & 0xFFFF0000u),  vv[cs_m+8][2*j + 1], a1b);
            }
            br[cp_m][cs_m]     += a0a + a0b;
            br[cp_m][cs_m + 8] += a1a + a1b;
            __syncthreads();
        }
    }
}

extern "C" void kernel_launch(void* const* d_in, const int* in_sizes, int n_in,
                              void* d_out, int out_size, void* d_ws, size_t ws_size,
                              hipStream_t stream)
{
    const float* x  = (const float*)d_in[0];
    const float* w1 = (const float*)d_in[1];
    const float* b1 = (const float*)d_in[2];
    const float* w2 = (const float*)d_in[3];
    const float* b2 = (const float*)d_in[4];
    float* outp = (float*)d_out;

    char* ws = (char*)d_ws;
    __bf16* ysq   = (__bf16*)(ws);                 // 4,194,304
    __bf16* xThi  = (__bf16*)(ws + 4194304);       // 1,048,576
    __bf16* xTlo  = (__bf16*)(ws + 5242880);       // 1,048,576
    __bf16* w1Thi = (__bf16*)(ws + 6291456);       //   294,912
    __bf16* w1Tlo = (__bf16*)(ws + 6586368);       //   294,912
    __bf16* w2hi  = (__bf16*)(ws + 6881280);       //    12,288
    __bf16* w2lo  = (__bf16*)(ws + 6893568);       // total < 8 MB ws

    k0_prep<<<417, 256, 0, stream>>>(x, w1, w2, xThi, xTlo, w1Thi, w1Tlo, w2hi, w2lo);
    k1_mfma<<<512, 256, 0, stream>>>(xThi, xTlo, w1Thi, w1Tlo, b1, ysq);
    k2_conv2_routing<<<NB * NL, 256, 0, stream>>>(ysq, w2hi, w2lo, b2, outp);
}